// Round 1
// baseline (304.656 us; speedup 1.0000x reference)
//
#include <hip/hip_runtime.h>

typedef __attribute__((ext_vector_type(4))) float f32x4;
typedef __attribute__((ext_vector_type(4))) unsigned int u32x4;
typedef __attribute__((ext_vector_type(8))) short s16x8;

#define B_  128
#define P_  196
#define E_  2048
#define D_  512
#define A_  512
#define M_  (B_*P_)   // 25088

// ---------------------------------------------------------------------------
// Kernel W: transpose + hi/lo-split We[E][A] -> WeT_hi/lo[A][E] (bf16 bits)
// ---------------------------------------------------------------------------
__global__ void we_conv_kernel(const float* __restrict__ We,
                               unsigned short* __restrict__ WeT_hi,
                               unsigned short* __restrict__ WeT_lo) {
  __shared__ float tile[32][33];
  const int tx = threadIdx.x, ty = threadIdx.y;
  const int a0 = blockIdx.x * 32, e0 = blockIdx.y * 32;
  tile[ty][tx] = We[(e0 + ty) * A_ + a0 + tx];
  __syncthreads();
  const float v = tile[tx][ty];              // = We[e0+tx][a0+ty]
  const unsigned int u = __float_as_uint(v);
  const unsigned short hi = (unsigned short)(u >> 16);
  const float lof = v - __uint_as_float(u & 0xffff0000u);
  const unsigned short lo = (unsigned short)(__float_as_uint(lof) >> 16);
  const int idx = (a0 + ty) * E_ + e0 + tx;  // WeT[a][e], coalesced over tx
  WeT_hi[idx] = hi;
  WeT_lo[idx] = lo;
}

// ---------------------------------------------------------------------------
// Kernel A: att2pb[b][a] = decoder_hidden[b] @ Wd + bd[a] + be[a]  (fp32)
// ---------------------------------------------------------------------------
__global__ void att2_kernel(const float* __restrict__ h, const float* __restrict__ Wd,
                            const float* __restrict__ bd, const float* __restrict__ be,
                            float* __restrict__ att2pb) {
  const int b = blockIdx.x;
  const int t = threadIdx.x;  // 256
  __shared__ float hs[D_];
  hs[t] = h[b * D_ + t];
  hs[t + 256] = h[b * D_ + t + 256];
  __syncthreads();
  float a0 = 0.f, a1 = 0.f;
  for (int d = 0; d < D_; ++d) {
    const float hv = hs[d];
    a0 = fmaf(hv, Wd[d * A_ + t], a0);
    a1 = fmaf(hv, Wd[d * A_ + t + 256], a1);
  }
  att2pb[b * A_ + t] = a0 + bd[t] + be[t];
  att2pb[b * A_ + t + 256] = a1 + bd[t + 256] + be[t + 256];
}

// ---------------------------------------------------------------------------
// split 8 fp32 -> bf16 hi (trunc) + bf16 lo (residual, trunc)
// ---------------------------------------------------------------------------
__device__ inline void split8(f32x4 u0, f32x4 u1, s16x8& hi, s16x8& lo) {
#pragma unroll
  for (int i = 0; i < 8; ++i) {
    const float v = (i < 4) ? u0[i] : u1[i - 4];
    const unsigned int u = __float_as_uint(v);
    hi[i] = (short)(u >> 16);
    const float lof = v - __uint_as_float(u & 0xffff0000u);
    lo[i] = (short)(__float_as_uint(lof) >> 16);
  }
}

// ---------------------------------------------------------------------------
// Kernel B: scores. 128x128 tile of att1 = enc @ We (split-bf16, 3-pass MFMA),
// epilogue: relu(att1 + att2pb) * Wf, row-sum -> att_part[row][8 slots]
// grid = (M/128)*4, bid = mb*4 + nb
// ---------------------------------------------------------------------------
#define LSTR 56   // LDS row stride in shorts (112B: 2-way bank aliasing = free)

__launch_bounds__(256, 2)
__global__ void score_kernel(const float* __restrict__ enc,
                             const unsigned short* __restrict__ WeT_hi,
                             const unsigned short* __restrict__ WeT_lo,
                             const float* __restrict__ att2pb,
                             const float* __restrict__ Wf,
                             float* __restrict__ att_part) {
  const int bid = blockIdx.x;
  const int mb = bid >> 2, nb = bid & 3;
  const int m0 = mb * 128, n0 = nb * 128;

  __shared__ unsigned short Ah[128 * LSTR];
  __shared__ unsigned short Al[128 * LSTR];
  __shared__ unsigned short Bh[128 * LSTR];
  __shared__ unsigned short Bl[128 * LSTR];

  const int t = threadIdx.x;
  const int lane = t & 63, w = t >> 6;
  const int wm = (w >> 1) * 64, wn = (w & 1) * 64;

  // staging: A tile [128 rows][32 k] f32; per thread rows (t>>2) and (t>>2)+64
  const int ar = t >> 2;
  const int akc = (t & 3) * 8;
  const float* aptr = enc + (m0 + ar) * E_ + akc;
  // B tile [128 n-rows][32 k] bf16 from WeT; per thread row t>>1, 16 shorts
  const int br = t >> 1;
  const int bkc = (t & 1) * 16;
  const unsigned short* bhp = WeT_hi + (n0 + br) * E_ + bkc;
  const unsigned short* blp = WeT_lo + (n0 + br) * E_ + bkc;

  unsigned short* AhW0 = Ah + ar * LSTR + akc;
  unsigned short* AlW0 = Al + ar * LSTR + akc;
  unsigned short* AhW1 = AhW0 + 64 * LSTR;
  unsigned short* AlW1 = AlW0 + 64 * LSTR;
  unsigned short* BhW = Bh + br * LSTR + bkc;
  unsigned short* BlW = Bl + br * LSTR + bkc;

  const f32x4 zero = {0.f, 0.f, 0.f, 0.f};
  f32x4 acc[4][4];
#pragma unroll
  for (int mi = 0; mi < 4; ++mi)
#pragma unroll
    for (int ni = 0; ni < 4; ++ni) acc[mi][ni] = zero;

  for (int k0 = 0; k0 < E_; k0 += 32) {
    // global loads
    const f32x4 a00 = *(const f32x4*)(aptr + k0);
    const f32x4 a01 = *(const f32x4*)(aptr + k0 + 4);
    const f32x4 a10 = *(const f32x4*)(aptr + k0 + 64 * E_);
    const f32x4 a11 = *(const f32x4*)(aptr + k0 + 64 * E_ + 4);
    const u32x4 bh0 = *(const u32x4*)(bhp + k0);
    const u32x4 bh1 = *(const u32x4*)(bhp + k0 + 8);
    const u32x4 bl0 = *(const u32x4*)(blp + k0);
    const u32x4 bl1 = *(const u32x4*)(blp + k0 + 8);

    s16x8 ah0, al0, ah1, al1;
    split8(a00, a01, ah0, al0);
    split8(a10, a11, ah1, al1);

    __syncthreads();   // previous iteration's fragment reads done
    *(s16x8*)AhW0 = ah0;  *(s16x8*)AlW0 = al0;
    *(s16x8*)AhW1 = ah1;  *(s16x8*)AlW1 = al1;
    *(u32x4*)BhW = bh0;   *(u32x4*)(BhW + 8) = bh1;
    *(u32x4*)BlW = bl0;   *(u32x4*)(BlW + 8) = bl1;
    __syncthreads();

    // fragments: lane&15 = row/col, (lane>>4)*8 = k offset
    const int koff = (lane >> 4) * 8;
    s16x8 fah[4], fal[4], fbh[4], fbl[4];
#pragma unroll
    for (int i = 0; i < 4; ++i) {
      const int arow = wm + i * 16 + (lane & 15);
      fah[i] = *(const s16x8*)(Ah + arow * LSTR + koff);
      fal[i] = *(const s16x8*)(Al + arow * LSTR + koff);
      const int brow = wn + i * 16 + (lane & 15);
      fbh[i] = *(const s16x8*)(Bh + brow * LSTR + koff);
      fbl[i] = *(const s16x8*)(Bl + brow * LSTR + koff);
    }
#pragma unroll
    for (int mi = 0; mi < 4; ++mi)
#pragma unroll
      for (int ni = 0; ni < 4; ++ni)
        acc[mi][ni] = __builtin_amdgcn_mfma_f32_16x16x32_bf16(fah[mi], fbh[ni], acc[mi][ni], 0, 0, 0);
#pragma unroll
    for (int mi = 0; mi < 4; ++mi)
#pragma unroll
      for (int ni = 0; ni < 4; ++ni)
        acc[mi][ni] = __builtin_amdgcn_mfma_f32_16x16x32_bf16(fal[mi], fbh[ni], acc[mi][ni], 0, 0, 0);
#pragma unroll
    for (int mi = 0; mi < 4; ++mi)
#pragma unroll
      for (int ni = 0; ni < 4; ++ni)
        acc[mi][ni] = __builtin_amdgcn_mfma_f32_16x16x32_bf16(fah[mi], fbl[ni], acc[mi][ni], 0, 0, 0);
  }

  // epilogue: x = acc + att2pb[b][col]; s = sum_col relu(x)*Wf[col]
  // C/D layout: col = lane&15, row = (lane>>4)*4 + reg   [m89/m91 verified]
  const int colL = wn + (lane & 15);
#pragma unroll
  for (int mi = 0; mi < 4; ++mi) {
    const int rowb = m0 + wm + mi * 16 + ((lane >> 4) << 2);
#pragma unroll
    for (int r = 0; r < 4; ++r) {
      const int row = rowb + r;
      const int bb = row / P_;
      float s = 0.f;
#pragma unroll
      for (int ni = 0; ni < 4; ++ni) {
        const int col = n0 + colL + ni * 16;
        const float v = acc[mi][ni][r] + att2pb[bb * A_ + col];
        s += fmaxf(v, 0.f) * Wf[col];
      }
#pragma unroll
      for (int off = 1; off < 16; off <<= 1) s += __shfl_xor(s, off);
      if ((lane & 15) == 0) att_part[row * 8 + nb * 2 + (w & 1)] = s;
    }
  }
}

// ---------------------------------------------------------------------------
// Kernel C: per (b, e-chunk): sum partials -> softmax over P -> alpha,
// awe[b][e] = sum_p alpha[p] * enc[b][p][e].  grid = B*2, block 256.
// ---------------------------------------------------------------------------
__global__ void softmax_awe_kernel(const float* __restrict__ enc,
                                   const float* __restrict__ att_part,
                                   float* __restrict__ out) {
  const int bid = blockIdx.x;
  const int b = bid >> 1, ch = bid & 1;
  const int t = threadIdx.x;
  __shared__ float sm[256];
  __shared__ float alpha_s[P_];

  float av = -1e30f;
  if (t < P_) {
    const float* ap = att_part + (b * P_ + t) * 8;
    float s = 0.f;
#pragma unroll
    for (int i = 0; i < 8; ++i) s += ap[i];
    av = s;
  }
  sm[t] = av;
  __syncthreads();
  for (int st = 128; st > 0; st >>= 1) {
    if (t < st) sm[t] = fmaxf(sm[t], sm[t + st]);
    __syncthreads();
  }
  const float mx = sm[0];
  __syncthreads();
  float ev = 0.f;
  if (t < P_) ev = __expf(av - mx);
  sm[t] = ev;
  __syncthreads();
  for (int st = 128; st > 0; st >>= 1) {
    if (t < st) sm[t] += sm[t + st];
    __syncthreads();
  }
  const float denom = sm[0];
  const float al = ev / denom;
  if (t < P_) {
    alpha_s[t] = al;
    if (ch == 0) out[B_ * E_ + b * P_ + t] = al;   // alpha output
  }
  __syncthreads();

  const int e0 = ch * 1024 + t * 4;
  const float* ebase = enc + b * P_ * E_ + e0;
  f32x4 acc = {0.f, 0.f, 0.f, 0.f};
  for (int p = 0; p < P_; ++p) {
    const f32x4 v = *(const f32x4*)(ebase + p * E_);
    const float a = alpha_s[p];
    acc.x += a * v.x; acc.y += a * v.y; acc.z += a * v.z; acc.w += a * v.w;
  }
  *(f32x4*)(out + b * E_ + e0) = acc;
}

// ---------------------------------------------------------------------------
extern "C" void kernel_launch(void* const* d_in, const int* in_sizes, int n_in,
                              void* d_out, int out_size, void* d_ws, size_t ws_size,
                              hipStream_t stream) {
  const float* enc = (const float*)d_in[0];
  const float* h   = (const float*)d_in[1];
  const float* We  = (const float*)d_in[2];
  const float* be  = (const float*)d_in[3];
  const float* Wd  = (const float*)d_in[4];
  const float* bd  = (const float*)d_in[5];
  const float* Wf  = (const float*)d_in[6];
  // d_in[7] = bf: constant shift before softmax -> cancels; unused.
  float* out = (float*)d_out;

  // workspace layout (~5.3 MB)
  float* att2pb = (float*)d_ws;                       // 128*512 f32
  float* att_part = att2pb + B_ * A_;                 // 25088*8 f32
  unsigned short* WeT_hi = (unsigned short*)(att_part + M_ * 8);  // 512*2048 u16
  unsigned short* WeT_lo = WeT_hi + A_ * E_;                      // 512*2048 u16

  we_conv_kernel<<<dim3(A_ / 32, E_ / 32), dim3(32, 32), 0, stream>>>(We, WeT_hi, WeT_lo);
  att2_kernel<<<B_, 256, 0, stream>>>(h, Wd, bd, be, att2pb);
  score_kernel<<<(M_ / 128) * 4, 256, 0, stream>>>(enc, WeT_hi, WeT_lo, att2pb, Wf, att_part);
  softmax_awe_kernel<<<B_ * 2, 256, 0, stream>>>(enc, att_part, out);
}